// Round 1
// 193.755 us; speedup vs baseline: 1.2845x; 1.2845x over previous
//
#include <hip/hip_runtime.h>

#define BB 32
#define KK 1024
#define DD 256

// Kernel 1: per-batch hilbert index + stable argsort via fully parallel
// counting-rank. One block per batch, 1024 threads (16 waves), 1 elem/thread.
//
// Stable rank of element k with 8-bit key:
//   rank = binbase[key]              (elements in smaller bins)
//        + waveoff[w][key]           (equal-key elements in earlier waves)
//        + popc(match & below_lane)  (equal-key elements earlier in this wave)
// Index order == (wave, lane) order, so this exactly reproduces the stable
// jnp.argsort of the previous (verified) serial counting sort.
__global__ __launch_bounds__(1024) void hilbert_order_kernel(
    const float* __restrict__ centroids,   // [B,K,2]
    float* __restrict__ order_out,         // [B,K] as float
    float* __restrict__ rev_out,           // [B,K] as float
    int* __restrict__ ws_order)            // [B,K] int scratch for gather
{
    __shared__ int hist16[16][256];   // per-wave histograms -> wave-exclusive offsets
    __shared__ int scanbuf[256];      // bin totals -> inclusive scan
    __shared__ int binbase[256];      // exclusive bin prefix

    const int b    = blockIdx.x;
    const int k    = threadIdx.x;     // element index 0..1023
    const int w    = k >> 6;          // wave id 0..15
    const int lane = k & 63;

    // Zero the per-wave histograms (4096 ints, 1024 threads).
    #pragma unroll
    for (int i = 0; i < 4; ++i) ((int*)hist16)[k + i * 1024] = 0;
    __syncthreads();

    // --- Hilbert key (identical arithmetic to the verified kernel) ---
    const float cxf = centroids[((size_t)b * KK + k) * 2 + 0];
    const float cyf = centroids[((size_t)b * KK + k) * 2 + 1];
    int x = (int)fminf(fmaxf(cxf * 15.0f, 0.0f), 15.0f);
    int y = (int)fminf(fmaxf(cyf * 15.0f, 0.0f), 15.0f);
    int d = 0;
    #pragma unroll
    for (int s = 8; s > 0; s >>= 1) {
        const int rx = ((x & s) != 0) ? 1 : 0;
        const int ry = ((y & s) != 0) ? 1 : 0;
        d += s * s * ((3 * rx) ^ ry);
        if (ry == 0) {
            if (rx == 1) {
                const int nx = s - 1 - y;
                const int ny = s - 1 - x;
                x = nx; y = ny;
            } else {
                const int tmp = x; x = y; y = tmp;
            }
        }
    }
    const int key = d;                // in [0,255]

    // --- Wave-level equal-key match mask via 8 ballots (wave64) ---
    unsigned long long match = ~0ull;
    #pragma unroll
    for (int bit = 0; bit < 8; ++bit) {
        const unsigned long long bb = __ballot((key >> bit) & 1);
        match &= ((key >> bit) & 1) ? bb : ~bb;
    }
    const unsigned long long below = (1ull << lane) - 1ull;  // lanes < me
    const int within = __popcll(match & below);
    // Leader lane of each equal-key group writes the group count (no atomics).
    if ((match & below) == 0ull) hist16[w][key] = __popcll(match);
    __syncthreads();

    // --- Per-bin: convert hist16 column to wave-exclusive prefix; bin totals ---
    int total = 0;
    if (k < 256) {
        #pragma unroll
        for (int ww = 0; ww < 16; ++ww) {
            const int c = hist16[ww][k];
            hist16[ww][k] = total;    // exclusive prefix over earlier waves
            total += c;
        }
        scanbuf[k] = total;
    }
    __syncthreads();

    // --- 256-bin Hillis-Steele inclusive scan (threads 0..255; uniform barriers) ---
    #pragma unroll
    for (int off = 1; off < 256; off <<= 1) {
        int v = 0;
        if (k < 256 && k >= off) v = scanbuf[k - off];
        __syncthreads();
        if (k < 256) scanbuf[k] += v;
        __syncthreads();
    }
    if (k < 256) binbase[k] = scanbuf[k] - total;  // exclusive bin base
    __syncthreads();

    // --- Final stable rank and direct output emit ---
    const int rank = binbase[key] + hist16[w][key] + within;

    order_out[b * KK + rank] = (float)k;   // order[rank] = k
    rev_out[b * KK + k]      = (float)rank; // reverse_order[k] = rank
    ws_order[b * KK + rank]  = k;
}

// Kernel 2: ordered_slots[b, r, :] = slots[b, order[b][r], :]
// 64 lanes per row (256 floats = 64 float4), 4 rows per 256-thread block.
__global__ __launch_bounds__(256) void gather_rows_kernel(
    const float4* __restrict__ slots,     // [B*K, 64] float4
    const int* __restrict__ ws_order,     // [B*K]
    float4* __restrict__ out)             // [B*K, 64] float4
{
    const int row  = blockIdx.x * 4 + (threadIdx.x >> 6);   // [0, B*K)
    const int lane = threadIdx.x & 63;
    const int b    = row >> 10;
    const int src  = ws_order[row];                          // wave-uniform
    const float4* sp = slots + ((size_t)(b * KK + src)) * (DD / 4);
    float4*       dp = out   + ((size_t)row) * (DD / 4);
    dp[lane] = sp[lane];
}

extern "C" void kernel_launch(void* const* d_in, const int* in_sizes, int n_in,
                              void* d_out, int out_size, void* d_ws, size_t ws_size,
                              hipStream_t stream) {
    const float* slots     = (const float*)d_in[0];   // [32,1024,256]
    // d_in[1] = adj  — unused by the reference; never read (128 MB saved)
    const float* centroids = (const float*)d_in[2];   // [32,1024,2]

    float* out          = (float*)d_out;
    float* ordered      = out;                               // 8388608 floats
    float* order_out    = out + (size_t)BB * KK * DD;        // 32768 floats
    float* rev_out      = order_out + (size_t)BB * KK;       // 32768 floats
    int*   ws_order     = (int*)d_ws;                        // 128 KB scratch

    hilbert_order_kernel<<<BB, 1024, 0, stream>>>(centroids, order_out, rev_out, ws_order);

    const int rows = BB * KK;                 // 32768 rows
    gather_rows_kernel<<<rows / 4, 256, 0, stream>>>(
        (const float4*)slots, ws_order, (float4*)ordered);
}

// Round 3
// 192.392 us; speedup vs baseline: 1.2936x; 1.0071x over previous
//
#include <hip/hip_runtime.h>

#define BB 32
#define KK 1024
#define DD 256

typedef float f32x4 __attribute__((ext_vector_type(4)));
typedef int   i32x4 __attribute__((ext_vector_type(4)));

// Kernel 1: per-batch hilbert index + stable argsort via fully parallel
// counting-rank. One block per batch, 1024 threads (16 waves), 1 elem/thread.
//
// Stable rank of element k with 8-bit key:
//   rank = binbase[key]              (elements in smaller bins)
//        + waveoff[w][key]           (equal-key elements in earlier waves)
//        + popc(match & below_lane)  (equal-key elements earlier in this wave)
__global__ __launch_bounds__(1024) void hilbert_order_kernel(
    const float* __restrict__ centroids,   // [B,K,2]
    float* __restrict__ order_out,         // [B,K] as float
    float* __restrict__ rev_out,           // [B,K] as float
    int* __restrict__ ws_order)            // [B,K] int scratch for gather
{
    __shared__ int hist16[16][256];   // per-wave histograms -> wave-exclusive offsets
    __shared__ int scanbuf[256];      // bin totals -> inclusive scan
    __shared__ int binbase[256];      // exclusive bin prefix

    const int b    = blockIdx.x;
    const int k    = threadIdx.x;     // element index 0..1023
    const int w    = k >> 6;          // wave id 0..15
    const int lane = k & 63;

    // Zero the per-wave histograms (4096 ints, 1024 threads).
    #pragma unroll
    for (int i = 0; i < 4; ++i) ((int*)hist16)[k + i * 1024] = 0;
    __syncthreads();

    // --- Hilbert key (identical arithmetic to the verified kernel) ---
    const float cxf = centroids[((size_t)b * KK + k) * 2 + 0];
    const float cyf = centroids[((size_t)b * KK + k) * 2 + 1];
    int x = (int)fminf(fmaxf(cxf * 15.0f, 0.0f), 15.0f);
    int y = (int)fminf(fmaxf(cyf * 15.0f, 0.0f), 15.0f);
    int d = 0;
    #pragma unroll
    for (int s = 8; s > 0; s >>= 1) {
        const int rx = ((x & s) != 0) ? 1 : 0;
        const int ry = ((y & s) != 0) ? 1 : 0;
        d += s * s * ((3 * rx) ^ ry);
        if (ry == 0) {
            if (rx == 1) {
                const int nx = s - 1 - y;
                const int ny = s - 1 - x;
                x = nx; y = ny;
            } else {
                const int tmp = x; x = y; y = tmp;
            }
        }
    }
    const int key = d;                // in [0,255]

    // --- Wave-level equal-key match mask via 8 ballots (wave64) ---
    unsigned long long match = ~0ull;
    #pragma unroll
    for (int bit = 0; bit < 8; ++bit) {
        const unsigned long long bb = __ballot((key >> bit) & 1);
        match &= ((key >> bit) & 1) ? bb : ~bb;
    }
    const unsigned long long below = (1ull << lane) - 1ull;  // lanes < me
    const int within = __popcll(match & below);
    // Leader lane of each equal-key group writes the group count (no atomics).
    if ((match & below) == 0ull) hist16[w][key] = __popcll(match);
    __syncthreads();

    // --- Per-bin: convert hist16 column to wave-exclusive prefix; bin totals ---
    int total = 0;
    if (k < 256) {
        #pragma unroll
        for (int ww = 0; ww < 16; ++ww) {
            const int c = hist16[ww][k];
            hist16[ww][k] = total;    // exclusive prefix over earlier waves
            total += c;
        }
        scanbuf[k] = total;
    }
    __syncthreads();

    // --- 256-bin Hillis-Steele inclusive scan (threads 0..255; uniform barriers) ---
    #pragma unroll
    for (int off = 1; off < 256; off <<= 1) {
        int v = 0;
        if (k < 256 && k >= off) v = scanbuf[k - off];
        __syncthreads();
        if (k < 256) scanbuf[k] += v;
        __syncthreads();
    }
    if (k < 256) binbase[k] = scanbuf[k] - total;  // exclusive bin base
    __syncthreads();

    // --- Final stable rank and direct output emit ---
    const int rank = binbase[key] + hist16[w][key] + within;

    order_out[b * KK + rank] = (float)k;    // order[rank] = k
    rev_out[b * KK + k]      = (float)rank; // reverse_order[k] = rank
    ws_order[b * KK + rank]  = k;
}

// Kernel 2: ordered_slots[b, r, :] = slots[b, order[b][r], :]
// One wave per 4 rows: indices fetched as a single int4 (one wave-uniform
// 16B load), then 4 independent 1KB-coalesced gather loads issued before
// any store (4x memory-level parallelism vs. the 1-row-per-wave version).
// Rows are read/written exactly once (permutation) -> non-temporal.
__global__ __launch_bounds__(256) void gather_rows_kernel(
    const f32x4* __restrict__ slots,      // [B*K, 64] float4
    const int* __restrict__ ws_order,     // [B*K]
    f32x4* __restrict__ out)              // [B*K, 64] float4
{
    const int gw   = blockIdx.x * 4 + (threadIdx.x >> 6);   // global wave id
    const int lane = threadIdx.x & 63;
    const int r0   = gw * 4;                                // first of 4 rows
    const int b    = r0 >> 10;                              // 1024 rows/batch, 4 | 1024

    const i32x4 idx = *reinterpret_cast<const i32x4*>(&ws_order[r0]);  // 16B aligned

    const f32x4* bp = slots + ((size_t)b << 10) * (DD / 4);

    const f32x4 v0 = __builtin_nontemporal_load(&bp[(size_t)idx.x * (DD / 4) + lane]);
    const f32x4 v1 = __builtin_nontemporal_load(&bp[(size_t)idx.y * (DD / 4) + lane]);
    const f32x4 v2 = __builtin_nontemporal_load(&bp[(size_t)idx.z * (DD / 4) + lane]);
    const f32x4 v3 = __builtin_nontemporal_load(&bp[(size_t)idx.w * (DD / 4) + lane]);

    f32x4* dp = out + (size_t)r0 * (DD / 4) + lane;
    __builtin_nontemporal_store(v0, dp + 0 * (DD / 4));
    __builtin_nontemporal_store(v1, dp + 1 * (DD / 4));
    __builtin_nontemporal_store(v2, dp + 2 * (DD / 4));
    __builtin_nontemporal_store(v3, dp + 3 * (DD / 4));
}

extern "C" void kernel_launch(void* const* d_in, const int* in_sizes, int n_in,
                              void* d_out, int out_size, void* d_ws, size_t ws_size,
                              hipStream_t stream) {
    const float* slots     = (const float*)d_in[0];   // [32,1024,256]
    // d_in[1] = adj  — unused by the reference; never read (128 MB saved)
    const float* centroids = (const float*)d_in[2];   // [32,1024,2]

    float* out          = (float*)d_out;
    float* ordered      = out;                               // 8388608 floats
    float* order_out    = out + (size_t)BB * KK * DD;        // 32768 floats
    float* rev_out      = order_out + (size_t)BB * KK;       // 32768 floats
    int*   ws_order     = (int*)d_ws;                        // 128 KB scratch

    hilbert_order_kernel<<<BB, 1024, 0, stream>>>(centroids, order_out, rev_out, ws_order);

    // 32768 rows / 4 rows-per-wave / 4 waves-per-block = 2048 blocks
    gather_rows_kernel<<<(BB * KK) / 16, 256, 0, stream>>>(
        (const f32x4*)slots, ws_order, (f32x4*)ordered);
}